// Round 1
// baseline (15820.618 us; speedup 1.0000x reference)
//
#include <hip/hip_runtime.h>

typedef unsigned short u16;
typedef unsigned int u32;
typedef __attribute__((ext_vector_type(8))) short short8;
typedef __attribute__((ext_vector_type(4))) float f32x4;

#define B_ 64
#define T_ 1024
#define D2_ 512
#define HD_ 256
#define G4_ 1024
#define PD_ 100
#define KX_ 640
#define KO_ 768
#define LBL_ 96
#define LPAD_ 128

__device__ __forceinline__ float bf2f(u16 u) {
  u32 v = ((u32)u) << 16;
  return __builtin_bit_cast(float, v);
}
__device__ __forceinline__ u16 f2bf(float f) {
  u32 u = __builtin_bit_cast(u32, f);
  u32 r = (u + 0x7fffu + ((u >> 16) & 1u)) >> 16;
  return (u16)r;
}
__device__ __forceinline__ float sigm(float x) { return 1.f / (1.f + expf(-x)); }

// ---------------- K0: weight prep (f32 -> bf16, padding, bias fuse) ----------
__global__ __launch_bounds__(256) void k_prep(
    const float* combW, const float* Wih, const float* bih, const float* Whh,
    const float* bhh, const float* linW, u16* wc, u16* wih, u16* whh, u16* wlin,
    float* biasg) {
  int idx = blockIdx.x * 256 + threadIdx.x;
  if (idx < 256 * KX_) {  // comb_W [256][612] -> [256][640] zero-padded
    int r = idx / KX_, c = idx % KX_;
    wc[idx] = f2bf(c < 612 ? combW[r * 612 + c] : 0.f);
    return;
  }
  idx -= 256 * KX_;
  if (idx < G4_ * HD_) { wih[idx] = f2bf(Wih[idx]); return; }
  idx -= G4_ * HD_;
  if (idx < G4_ * HD_) { whh[idx] = f2bf(Whh[idx]); return; }
  idx -= G4_ * HD_;
  if (idx < LPAD_ * KO_) {  // lin_W [96][768] -> [128][768] zero rows 96..127
    int r = idx / KO_;
    wlin[idx] = f2bf(r < LBL_ ? linW[idx] : 0.f);
    return;
  }
  idx -= LPAD_ * KO_;
  if (idx < G4_) biasg[idx] = bih[idx] + bhh[idx];
}

// ---------------- K1: prefix sums P[b][t][d] = sum_{u<t} enc[b][u][d] --------
__global__ __launch_bounds__(256) void k_prefix(const float* enc, float* P) {
  int id = blockIdx.x * 256 + threadIdx.x;  // 32768 threads
  int b = id >> 9, d = id & 511;
  const float* e = enc + (size_t)b * T_ * D2_ + d;
  float* p = P + (size_t)b * T_ * D2_ + d;
  float acc = 0.f;
  for (int t = 0; t < T_; ++t) {
    p[(size_t)t * D2_] = acc;
    acc += e[(size_t)t * D2_];
  }
}

// ---------------- K2: X rows [pe(100) | avg(512) | 0-pad(28)] as bf16 --------
__global__ __launch_bounds__(256) void k_xbuild(const float* P, const float* ptab,
                                                const int* pid, const int* sidx,
                                                u16* X) {
  int m = blockIdx.x;  // m = t*64 + b
  int t = m >> 6, b = m & 63;
  int pp = 0, ps = 0;
  if (t > 0) {
    pp = pid[(t - 1) * B_ + b];
    ps = sidx[(t - 1) * B_ + b];
  }
  bool valid = (ps >= 0) && (t > 0);
  int start = min(ps, t - 1);
  if (start < 0) start = 0;
  if (start > T_ - 1) start = T_ - 1;
  float invlen = 1.f / (float)max(t - start, 1);
  const float* Pt = P + ((size_t)b * T_ + t) * D2_;
  const float* Psrc = P + ((size_t)b * T_ + start) * D2_;
  u16* xr = X + (size_t)m * KX_;
  for (int k = threadIdx.x; k < KX_; k += 256) {
    float v;
    if (k < PD_) v = ptab[pp * PD_ + k];
    else if (k < 612) {
      int d = k - PD_;
      v = valid ? (Pt[d] - Psrc[d]) * invlen : 0.f;
    } else v = 0.f;
    xr[k] = f2bf(v);
  }
}

// ---------------- generic 64x64-tile bf16 MFMA GEMM: out = A @ Bw^T ----------
// MODE 0: Z = tanh(X@Wc^T + comb_b), zero rows m<64 (t==0), bf16 out, N=256
// MODE 1: G = Z@Wih^T + biasg, bf16 out, N=1024
// MODE 2: Out = [H|enc]@lin^T, f32 out to d_out (cols<96), -1e10 fixup, N=128
template <int MODE>
__global__ __launch_bounds__(256) void k_gemm(const u16* A, const float* A2f,
                                              const u16* Bw, int K, int lda,
                                              const float* bias, u16* outb,
                                              float* outf) {
  __shared__ u16 As[64][40];
  __shared__ u16 Bs[64][40];
  const int m0 = blockIdx.x * 64, n0 = blockIdx.y * 64;
  const int tid = threadIdx.x;
  const int srow = tid >> 2, sc8 = (tid & 3) * 8;
  const int w = tid >> 6, l = tid & 63;
  const int l15 = l & 15, lh = l >> 4;
  f32x4 acc[4] = {};
  for (int k0 = 0; k0 < K; k0 += 32) {
    int k = k0 + sc8;
    uint4 av;
    if constexpr (MODE == 2) {
      if (k < 256) {
        av = *(const uint4*)(A + (size_t)(m0 + srow) * 256 + k);
      } else {
        const float* src = A2f + (size_t)(m0 + srow) * 512 + (k - 256);
        float4 f0 = *(const float4*)(src);
        float4 f1 = *(const float4*)(src + 4);
        av.x = (u32)f2bf(f0.x) | ((u32)f2bf(f0.y) << 16);
        av.y = (u32)f2bf(f0.z) | ((u32)f2bf(f0.w) << 16);
        av.z = (u32)f2bf(f1.x) | ((u32)f2bf(f1.y) << 16);
        av.w = (u32)f2bf(f1.z) | ((u32)f2bf(f1.w) << 16);
      }
    } else {
      av = *(const uint4*)(A + (size_t)(m0 + srow) * lda + k);
    }
    *(uint4*)&As[srow][sc8] = av;
    uint4 bv = *(const uint4*)(Bw + (size_t)(n0 + srow) * K + k);
    *(uint4*)&Bs[srow][sc8] = bv;
    __syncthreads();
    short8 a8 = *(const short8*)&As[16 * w + l15][lh * 8];
#pragma unroll
    for (int nt = 0; nt < 4; ++nt) {
      short8 b8 = *(const short8*)&Bs[nt * 16 + l15][lh * 8];
      acc[nt] = __builtin_amdgcn_mfma_f32_16x16x32_bf16(a8, b8, acc[nt], 0, 0, 0);
    }
    __syncthreads();
  }
#pragma unroll
  for (int nt = 0; nt < 4; ++nt) {
#pragma unroll
    for (int r = 0; r < 4; ++r) {
      int gm = m0 + 16 * w + lh * 4 + r;
      int gn = n0 + nt * 16 + l15;
      float v = acc[nt][r];
      if constexpr (MODE == 0) {
        v = tanhf(v + bias[gn]);
        if (gm < 64) v = 0.f;  // t == 0 rows
        outb[(size_t)gm * 256 + gn] = f2bf(v);
      } else if constexpr (MODE == 1) {
        v += bias[gn];
        outb[(size_t)gm * 1024 + gn] = f2bf(v);
      } else {
        if (gn < LBL_) {
          if ((gm & (T_ - 1)) == 0 && gn == 1) v = -1e10f;
          outf[(size_t)gm * LBL_ + gn] = v;
        }
      }
    }
  }
}

// ---------------- K5: sequential LSTM, one block per batch -------------------
__global__ __launch_bounds__(1024) void k_seq(const u16* G, const u16* Whh,
                                              u16* Hout) {
  __shared__ float hs[256];
  __shared__ float gl[1024];
  const int b = blockIdx.x;
  const int tid = threadIdx.x;
  float c = 0.f;
  if (tid < 256) hs[tid] = 0.f;
  __syncthreads();
  const u16* wr = Whh + (size_t)tid * 256;
  for (int t = 0; t < T_; ++t) {
    float acc = bf2f(G[((size_t)t * 64 + b) * 1024 + tid]);
#pragma unroll 4
    for (int k = 0; k < 256; k += 8) {
      uint4 wv = *(const uint4*)(wr + k);
      float4 h0 = *(const float4*)&hs[k];
      float4 h1 = *(const float4*)&hs[k + 4];
      acc = fmaf(__builtin_bit_cast(float, wv.x << 16), h0.x, acc);
      acc = fmaf(__builtin_bit_cast(float, wv.x & 0xffff0000u), h0.y, acc);
      acc = fmaf(__builtin_bit_cast(float, wv.y << 16), h0.z, acc);
      acc = fmaf(__builtin_bit_cast(float, wv.y & 0xffff0000u), h0.w, acc);
      acc = fmaf(__builtin_bit_cast(float, wv.z << 16), h1.x, acc);
      acc = fmaf(__builtin_bit_cast(float, wv.z & 0xffff0000u), h1.y, acc);
      acc = fmaf(__builtin_bit_cast(float, wv.w << 16), h1.z, acc);
      acc = fmaf(__builtin_bit_cast(float, wv.w & 0xffff0000u), h1.w, acc);
    }
    gl[tid] = acc;
    __syncthreads();
    if (tid < 256) {
      float gi = gl[tid], gf = gl[tid + 256], gg = gl[tid + 512], go = gl[tid + 768];
      c = sigm(gf) * c + sigm(gi) * tanhf(gg);
      float hn = sigm(go) * tanhf(c);
      hs[tid] = hn;
      Hout[((size_t)b * T_ + t) * 256 + tid] = f2bf(hn);
    }
    __syncthreads();
  }
}

// ---------------- K7: in-place row log-softmax on d_out (rows of 96) ---------
__global__ __launch_bounds__(256) void k_lsm(float* out) {
  int row = blockIdx.x * 4 + (threadIdx.x >> 6);
  int l = threadIdx.x & 63;
  float* r = out + (size_t)row * LBL_;
  float v0 = r[l];
  float v1 = (l < 32) ? r[64 + l] : -__builtin_inff();
  float mx = fmaxf(v0, v1);
#pragma unroll
  for (int s = 32; s; s >>= 1) mx = fmaxf(mx, __shfl_xor(mx, s));
  float s0 = expf(v0 - mx) + ((l < 32) ? expf(v1 - mx) : 0.f);
#pragma unroll
  for (int s = 32; s; s >>= 1) s0 += __shfl_xor(s0, s);
  float lg = logf(s0) + mx;
  r[l] = v0 - lg;
  if (l < 32) r[64 + l] = v1 - lg;
}

extern "C" void kernel_launch(void* const* d_in, const int* in_sizes, int n_in,
                              void* d_out, int out_size, void* d_ws, size_t ws_size,
                              hipStream_t stream) {
  const float* enc = (const float*)d_in[0];
  const float* ptab = (const float*)d_in[1];
  const float* Wih = (const float*)d_in[2];
  const float* bih = (const float*)d_in[3];
  const float* Whh = (const float*)d_in[4];
  const float* bhh = (const float*)d_in[5];
  const float* combW = (const float*)d_in[6];
  const float* combb = (const float*)d_in[7];
  const float* linW = (const float*)d_in[8];
  const int* pid = (const int*)d_in[9];
  const int* sidx = (const int*)d_in[10];

  char* ws = (char*)d_ws;
  size_t off = 0;
  auto alloc = [&](size_t bytes) {
    void* p = ws + off;
    off += (bytes + 255) & ~(size_t)255;
    return p;
  };
  // region1: P (f32, 128MB) -> later aliased by G (bf16, 128MB)
  float* P = (float*)alloc((size_t)B_ * T_ * D2_ * 4);
  // region2: X (bf16, 80MB) -> later aliased by H (bf16, 32MB)
  u16* Xb = (u16*)alloc((size_t)T_ * B_ * KX_ * 2);
  u16* Z = (u16*)alloc((size_t)T_ * B_ * HD_ * 2);
  u16* wc = (u16*)alloc(256 * KX_ * 2);
  u16* wih = (u16*)alloc(G4_ * HD_ * 2);
  u16* whh = (u16*)alloc(G4_ * HD_ * 2);
  u16* wlin = (u16*)alloc(LPAD_ * KO_ * 2);
  float* biasg = (float*)alloc(G4_ * 4);
  u16* G = (u16*)P;    // alias: P dead after k_xbuild
  u16* Hs = (u16*)Xb;  // alias: X dead after k_gemm<0>
  float* out = (float*)d_out;

  k_prep<<<3076, 256, 0, stream>>>(combW, Wih, bih, Whh, bhh, linW, wc, wih, whh,
                                   wlin, biasg);
  k_prefix<<<128, 256, 0, stream>>>(enc, P);
  k_xbuild<<<T_ * B_, 256, 0, stream>>>(P, ptab, pid, sidx, Xb);
  dim3 g3(1024, 4);
  k_gemm<0><<<g3, 256, 0, stream>>>(Xb, nullptr, wc, KX_, KX_, combb, Z, nullptr);
  dim3 g4(1024, 16);
  k_gemm<1><<<g4, 256, 0, stream>>>(Z, nullptr, wih, HD_, HD_, biasg, G, nullptr);
  k_seq<<<B_, 1024, 0, stream>>>(G, whh, Hs);
  dim3 g6(1024, 2);
  k_gemm<2><<<g6, 256, 0, stream>>>(Hs, enc, wlin, KO_, 0, nullptr, nullptr, out);
  k_lsm<<<(T_ * B_) / 4, 256, 0, stream>>>(out);
}

// Round 2
// 3487.581 us; speedup vs baseline: 4.5363x; 4.5363x over previous
//
#include <hip/hip_runtime.h>

typedef unsigned short u16;
typedef unsigned int u32;
typedef unsigned long long u64;
typedef __attribute__((ext_vector_type(8))) short short8;
typedef __attribute__((ext_vector_type(4))) float f32x4;
typedef __attribute__((ext_vector_type(2))) _Float16 f16x2;

#define B_ 64
#define T_ 1024
#define D2_ 512
#define HD_ 256
#define G4_ 1024
#define PD_ 100
#define KX_ 640
#define KO_ 768
#define LBL_ 96
#define LPAD_ 128

// k_seq geometry: per row, RREG f16-pairs in VGPRs, QL u64 slots (2 pairs each) in LDS
#define RREG 104
#define QL 12

__device__ __forceinline__ float bf2f(u16 u) {
  u32 v = ((u32)u) << 16;
  return __builtin_bit_cast(float, v);
}
__device__ __forceinline__ u16 f2bf(float f) {
  u32 u = __builtin_bit_cast(u32, f);
  u32 r = (u + 0x7fffu + ((u >> 16) & 1u)) >> 16;
  return (u16)r;
}
__device__ __forceinline__ float sigm(float x) { return 1.f / (1.f + expf(-x)); }
__device__ __forceinline__ float dot2(u32 w, u32 h, float acc) {
  return __builtin_amdgcn_fdot2(__builtin_bit_cast(f16x2, w),
                                __builtin_bit_cast(f16x2, h), acc, false);
}
__device__ __forceinline__ u32 pkf16(float a, float b) {
  return __builtin_bit_cast(u32, __builtin_amdgcn_cvt_pkrtz(a, b));
}

// ---------------- K0: weight prep ----------------
// wc: comb_W bf16 [256][640] padded; wt: W_hh f16-pair [128][1024] transposed;
// wih: W_ih bf16; wlin: lin_W bf16 [128][768]; biasg = b_ih + b_hh
__global__ __launch_bounds__(256) void k_prep(
    const float* combW, const float* Wih, const float* bih, const float* Whh,
    const float* bhh, const float* linW, u16* wc, u16* wih, u32* wt, u16* wlin,
    float* biasg) {
  int idx = blockIdx.x * 256 + threadIdx.x;
  if (idx < 256 * KX_) {
    int r = idx / KX_, c = idx % KX_;
    wc[idx] = f2bf(c < 612 ? combW[r * 612 + c] : 0.f);
    return;
  }
  idx -= 256 * KX_;
  if (idx < 128 * 1024) {  // wt[p][r] = pack_f16(Whh[r][2p], Whh[r][2p+1])
    int p = idx >> 10, r = idx & 1023;
    wt[idx] = pkf16(Whh[r * 256 + 2 * p], Whh[r * 256 + 2 * p + 1]);
    return;
  }
  idx -= 128 * 1024;
  if (idx < G4_ * HD_) { wih[idx] = f2bf(Wih[idx]); return; }
  idx -= G4_ * HD_;
  if (idx < LPAD_ * KO_) {
    int r = idx / KO_;
    wlin[idx] = f2bf(r < LBL_ ? linW[idx] : 0.f);
    return;
  }
  idx -= LPAD_ * KO_;
  if (idx < G4_) biasg[idx] = bih[idx] + bhh[idx];
}

// ---------------- K1: prefix sums ----------------
__global__ __launch_bounds__(256) void k_prefix(const float* enc, float* P) {
  int id = blockIdx.x * 256 + threadIdx.x;
  int b = id >> 9, d = id & 511;
  const float* e = enc + (size_t)b * T_ * D2_ + d;
  float* p = P + (size_t)b * T_ * D2_ + d;
  float acc = 0.f;
  for (int t = 0; t < T_; ++t) {
    p[(size_t)t * D2_] = acc;
    acc += e[(size_t)t * D2_];
  }
}

// ---------------- K2: X rows [pe(100) | avg(512) | pad(28)] bf16 -------------
__global__ __launch_bounds__(256) void k_xbuild(const float* P, const float* ptab,
                                                const int* pid, const int* sidx,
                                                u16* X) {
  int m = blockIdx.x;  // m = t*64 + b
  int t = m >> 6, b = m & 63;
  int pp = 0, ps = 0;
  if (t > 0) {
    pp = pid[(t - 1) * B_ + b];
    ps = sidx[(t - 1) * B_ + b];
  }
  bool valid = (ps >= 0) && (t > 0);
  int start = min(ps, t - 1);
  if (start < 0) start = 0;
  if (start > T_ - 1) start = T_ - 1;
  float invlen = 1.f / (float)max(t - start, 1);
  const float* Pt = P + ((size_t)b * T_ + t) * D2_;
  const float* Psrc = P + ((size_t)b * T_ + start) * D2_;
  u16* xr = X + (size_t)m * KX_;
  for (int k = threadIdx.x; k < KX_; k += 256) {
    float v;
    if (k < PD_) v = ptab[pp * PD_ + k];
    else if (k < 612) {
      int d = k - PD_;
      v = valid ? (Pt[d] - Psrc[d]) * invlen : 0.f;
    } else v = 0.f;
    xr[k] = f2bf(v);
  }
}

// ---------------- generic 64x64-tile bf16 MFMA GEMM: out = A @ Bw^T ----------
template <int MODE>
__global__ __launch_bounds__(256) void k_gemm(const u16* A, const float* A2f,
                                              const u16* Bw, int K, int lda,
                                              const float* bias, u16* outb,
                                              float* outf) {
  __shared__ u16 As[64][40];
  __shared__ u16 Bs[64][40];
  const int m0 = blockIdx.x * 64, n0 = blockIdx.y * 64;
  const int tid = threadIdx.x;
  const int srow = tid >> 2, sc8 = (tid & 3) * 8;
  const int w = tid >> 6, l = tid & 63;
  const int l15 = l & 15, lh = l >> 4;
  f32x4 acc[4] = {};
  for (int k0 = 0; k0 < K; k0 += 32) {
    int k = k0 + sc8;
    uint4 av;
    if constexpr (MODE == 2) {
      if (k < 256) {
        av = *(const uint4*)(A + (size_t)(m0 + srow) * 256 + k);
      } else {
        const float* src = A2f + (size_t)(m0 + srow) * 512 + (k - 256);
        float4 f0 = *(const float4*)(src);
        float4 f1 = *(const float4*)(src + 4);
        av.x = (u32)f2bf(f0.x) | ((u32)f2bf(f0.y) << 16);
        av.y = (u32)f2bf(f0.z) | ((u32)f2bf(f0.w) << 16);
        av.z = (u32)f2bf(f1.x) | ((u32)f2bf(f1.y) << 16);
        av.w = (u32)f2bf(f1.z) | ((u32)f2bf(f1.w) << 16);
      }
    } else {
      av = *(const uint4*)(A + (size_t)(m0 + srow) * lda + k);
    }
    *(uint4*)&As[srow][sc8] = av;
    uint4 bv = *(const uint4*)(Bw + (size_t)(n0 + srow) * K + k);
    *(uint4*)&Bs[srow][sc8] = bv;
    __syncthreads();
    short8 a8 = *(const short8*)&As[16 * w + l15][lh * 8];
#pragma unroll
    for (int nt = 0; nt < 4; ++nt) {
      short8 b8 = *(const short8*)&Bs[nt * 16 + l15][lh * 8];
      acc[nt] = __builtin_amdgcn_mfma_f32_16x16x32_bf16(a8, b8, acc[nt], 0, 0, 0);
    }
    __syncthreads();
  }
#pragma unroll
  for (int nt = 0; nt < 4; ++nt) {
#pragma unroll
    for (int r = 0; r < 4; ++r) {
      int gm = m0 + 16 * w + lh * 4 + r;
      int gn = n0 + nt * 16 + l15;
      float v = acc[nt][r];
      if constexpr (MODE == 0) {
        v = tanhf(v + bias[gn]);
        if (gm < 64) v = 0.f;
        outb[(size_t)gm * 256 + gn] = f2bf(v);
      } else if constexpr (MODE == 1) {
        v += bias[gn];
        outb[(size_t)gm * 1024 + gn] = f2bf(v);
      } else {
        if (gn < LBL_) {
          if ((gm & (T_ - 1)) == 0 && gn == 1) v = -1e10f;
          outf[(size_t)gm * LBL_ + gn] = v;
        }
      }
    }
  }
}

// ---------------- K5: sequential LSTM, weights register/LDS-resident ---------
// 512 threads per batch; thread t owns gate rows t and t+512.
__global__ __launch_bounds__(512, 2) void k_seq(const u16* G, const u32* wt,
                                                u32* Hout) {
  __shared__ u64 w2[QL][1024];           // 96 KB: pairs RREG..127 of each row
  __shared__ float gl[1024];             // gates exchange
  __shared__ __align__(16) u32 hp[128];  // h as f16 pairs
  const int b = blockIdx.x;
  const int t0 = threadIdx.x;
  u32 wr1[RREG], wr2[RREG];
#pragma unroll
  for (int p = 0; p < RREG; ++p) {
    wr1[p] = wt[p * 1024 + t0];
    wr2[p] = wt[p * 1024 + t0 + 512];
  }
#pragma unroll
  for (int q = 0; q < QL; ++q) {
    int p0 = RREG + 2 * q;
    u32 a0 = wt[p0 * 1024 + t0], a1 = wt[(p0 + 1) * 1024 + t0];
    w2[q][t0] = ((u64)a1 << 32) | a0;
    u32 b0 = wt[p0 * 1024 + t0 + 512], b1 = wt[(p0 + 1) * 1024 + t0 + 512];
    w2[q][t0 + 512] = ((u64)b1 << 32) | b0;
  }
  if (t0 < 128) hp[t0] = 0;
  float c0 = 0.f, c1 = 0.f;
  const u16* gptr = G + (size_t)b * 1024 + t0;  // + t*65536 per step
  u16 g1 = gptr[0], g2 = gptr[512];
  __syncthreads();
  for (int t = 0; t < T_; ++t) {
    u16 n1 = 0, n2 = 0;
    if (t + 1 < T_) {
      const u16* gp = gptr + (size_t)(t + 1) * 65536;
      n1 = gp[0];
      n2 = gp[512];
    }
    float a1a = bf2f(g1), a1b = 0.f, a2a = bf2f(g2), a2b = 0.f;
#pragma unroll
    for (int q = 0; q < 26; ++q) {  // pairs 0..103 from registers
      uint4 h4 = *(const uint4*)&hp[4 * q];
      if (q & 1) {
        a1b = dot2(wr1[4 * q + 0], h4.x, a1b);
        a2b = dot2(wr2[4 * q + 0], h4.x, a2b);
        a1b = dot2(wr1[4 * q + 1], h4.y, a1b);
        a2b = dot2(wr2[4 * q + 1], h4.y, a2b);
        a1b = dot2(wr1[4 * q + 2], h4.z, a1b);
        a2b = dot2(wr2[4 * q + 2], h4.z, a2b);
        a1b = dot2(wr1[4 * q + 3], h4.w, a1b);
        a2b = dot2(wr2[4 * q + 3], h4.w, a2b);
      } else {
        a1a = dot2(wr1[4 * q + 0], h4.x, a1a);
        a2a = dot2(wr2[4 * q + 0], h4.x, a2a);
        a1a = dot2(wr1[4 * q + 1], h4.y, a1a);
        a2a = dot2(wr2[4 * q + 1], h4.y, a2a);
        a1a = dot2(wr1[4 * q + 2], h4.z, a1a);
        a2a = dot2(wr2[4 * q + 2], h4.z, a2a);
        a1a = dot2(wr1[4 * q + 3], h4.w, a1a);
        a2a = dot2(wr2[4 * q + 3], h4.w, a2a);
      }
    }
#pragma unroll
    for (int q = 0; q < QL; ++q) {  // pairs RREG..127 from LDS
      u64 wa = w2[q][t0], wb = w2[q][t0 + 512];
      u64 hq = *(const u64*)&hp[RREG + 2 * q];
      u32 hx = (u32)hq, hy = (u32)(hq >> 32);
      if (q & 1) {
        a1b = dot2((u32)wa, hx, a1b);
        a1b = dot2((u32)(wa >> 32), hy, a1b);
        a2b = dot2((u32)wb, hx, a2b);
        a2b = dot2((u32)(wb >> 32), hy, a2b);
      } else {
        a1a = dot2((u32)wa, hx, a1a);
        a1a = dot2((u32)(wa >> 32), hy, a1a);
        a2a = dot2((u32)wb, hx, a2a);
        a2a = dot2((u32)(wb >> 32), hy, a2a);
      }
    }
    gl[t0] = a1a + a1b;
    gl[t0 + 512] = a2a + a2b;
    __syncthreads();
    if (t0 < 128) {
      int j2 = 2 * t0;
      float gi0 = gl[j2], gi1 = gl[j2 + 1];
      float gf0 = gl[j2 + 256], gf1 = gl[j2 + 257];
      float gg0 = gl[j2 + 512], gg1 = gl[j2 + 513];
      float go0 = gl[j2 + 768], go1 = gl[j2 + 769];
      c0 = sigm(gf0) * c0 + sigm(gi0) * tanhf(gg0);
      c1 = sigm(gf1) * c1 + sigm(gi1) * tanhf(gg1);
      float h0 = sigm(go0) * tanhf(c0);
      float h1 = sigm(go1) * tanhf(c1);
      hp[t0] = pkf16(h0, h1);
      Hout[((size_t)b * 1024 + t) * 128 + t0] = ((u32)f2bf(h1) << 16) | f2bf(h0);
    }
    g1 = n1;
    g2 = n2;
    __syncthreads();
  }
}

// ---------------- K7: in-place row log-softmax on d_out ----------------------
__global__ __launch_bounds__(256) void k_lsm(float* out) {
  int row = blockIdx.x * 4 + (threadIdx.x >> 6);
  int l = threadIdx.x & 63;
  float* r = out + (size_t)row * LBL_;
  float v0 = r[l];
  float v1 = (l < 32) ? r[64 + l] : -__builtin_inff();
  float mx = fmaxf(v0, v1);
#pragma unroll
  for (int s = 32; s; s >>= 1) mx = fmaxf(mx, __shfl_xor(mx, s));
  float s0 = expf(v0 - mx) + ((l < 32) ? expf(v1 - mx) : 0.f);
#pragma unroll
  for (int s = 32; s; s >>= 1) s0 += __shfl_xor(s0, s);
  float lg = logf(s0) + mx;
  r[l] = v0 - lg;
  if (l < 32) r[64 + l] = v1 - lg;
}

extern "C" void kernel_launch(void* const* d_in, const int* in_sizes, int n_in,
                              void* d_out, int out_size, void* d_ws, size_t ws_size,
                              hipStream_t stream) {
  const float* enc = (const float*)d_in[0];
  const float* ptab = (const float*)d_in[1];
  const float* Wih = (const float*)d_in[2];
  const float* bih = (const float*)d_in[3];
  const float* Whh = (const float*)d_in[4];
  const float* bhh = (const float*)d_in[5];
  const float* combW = (const float*)d_in[6];
  const float* combb = (const float*)d_in[7];
  const float* linW = (const float*)d_in[8];
  const int* pid = (const int*)d_in[9];
  const int* sidx = (const int*)d_in[10];

  char* ws = (char*)d_ws;
  size_t off = 0;
  auto alloc = [&](size_t bytes) {
    void* p = ws + off;
    off += (bytes + 255) & ~(size_t)255;
    return p;
  };
  float* P = (float*)alloc((size_t)B_ * T_ * D2_ * 4);   // -> aliased by G
  u16* Xb = (u16*)alloc((size_t)T_ * B_ * KX_ * 2);      // -> aliased by H
  u16* Z = (u16*)alloc((size_t)T_ * B_ * HD_ * 2);
  u16* wc = (u16*)alloc(256 * KX_ * 2);
  u16* wih = (u16*)alloc(G4_ * HD_ * 2);
  u32* wt = (u32*)alloc(128 * 1024 * 4);
  u16* wlin = (u16*)alloc(LPAD_ * KO_ * 2);
  float* biasg = (float*)alloc(G4_ * 4);
  u16* G = (u16*)P;
  u32* Hs = (u32*)Xb;
  float* out = (float*)d_out;

  k_prep<<<2564, 256, 0, stream>>>(combW, Wih, bih, Whh, bhh, linW, wc, wih, wt,
                                   wlin, biasg);
  k_prefix<<<128, 256, 0, stream>>>(enc, P);
  k_xbuild<<<T_ * B_, 256, 0, stream>>>(P, ptab, pid, sidx, Xb);
  dim3 g3(1024, 4);
  k_gemm<0><<<g3, 256, 0, stream>>>(Xb, nullptr, wc, KX_, KX_, combb, Z, nullptr);
  dim3 g4(1024, 16);
  k_gemm<1><<<g4, 256, 0, stream>>>(Z, nullptr, wih, HD_, HD_, biasg, G, nullptr);
  k_seq<<<B_, 512, 0, stream>>>(G, wt, (u32*)Hs);
  dim3 g6(1024, 2);
  k_gemm<2><<<g6, 256, 0, stream>>>((const u16*)Hs, enc, wlin, KO_, 0, nullptr,
                                    nullptr, out);
  k_lsm<<<(T_ * B_) / 4, 256, 0, stream>>>(out);
}